// Round 5
// baseline (949.387 us; speedup 1.0000x reference)
//
#include <hip/hip_runtime.h>

// Exact DTW, single-wave workgroups, register-systolic handoff, no barriers.
// GG WGs x 64 lanes; lane t owns RR=4096/(64*GG) rows; columns in chunks of
// C=8; lane t runs chunk c at step s=t+c. Neighbor bottom-row handoff is a
// tail-of-step __shfl_up (register dataflow, wave-lockstep => no barrier, no
// LDS ordering hazard). Cross-WG boundaries stream through d_ws with a
// release-flag per 8 chunks (flag delayed 2 chunks so the release's vmcnt
// drain hits retired stores); consumers prefetch 1 block ahead into per-lane
// registers and route to lane 0 via shuffles at the tail.

#define N     4096
#define TPB   64
#define C     8
#define NCH   (N / C)           // 512 chunks
#define BCH   8                 // chunks per flag block
#define BLKF  (BCH * C)         // 64 floats per block (1 per lane)
#define NBLK  (NCH / BCH)       // 64 blocks
#define LSTEPS (NCH + TPB - 1)  // 575
#define BIG   1e30f
#define YIDX(j) ((j) + (((j) >> 5) << 2))   // 16B pad per 32 floats

template <int GG>
__global__ __launch_bounds__(TPB, 1)
void dtw_wavepipe(const float* __restrict__ xg, const float* __restrict__ yg,
                  float* __restrict__ out, float* __restrict__ gbuf,
                  int* __restrict__ flags) {
    constexpr int RR = N / (TPB * GG);      // rows per lane
    __shared__ float ylds[N + (N >> 5) * 4];

    const int t = threadIdx.x;
    const int g = blockIdx.x;

    for (int j4 = t * 4; j4 < N; j4 += TPB * 4)
        *(float4*)&ylds[YIDX(j4)] = *(const float4*)&yg[j4];
    __syncthreads();   // single wave: compiles to waitcnt (barrier elided/cheap)

    float x[RR], carry[RR];
    const int i0 = g * (N / GG) + t * RR;
#pragma unroll
    for (int r = 0; r < RR; ++r) { x[r] = xg[i0 + r]; carry[r] = BIG; }

    float diagc = (g == 0 && t == 0) ? 0.0f : BIG;   // (0,0): min(BIG,BIG,0)=0
    float nb[C];
    float rv_cur = BIG, rv_next = BIG;
    const float* nbsrc  = gbuf  + (size_t)(g - 1) * N;   // valid iff g>0
    const int*   nbflag = flags + (g - 1) * NBLK;

    // prologue: consumers fetch boundary block 0
    if (GG > 1 && g > 0) {
        while (__hip_atomic_load(&nbflag[0], __ATOMIC_ACQUIRE,
                                 __HIP_MEMORY_SCOPE_AGENT) == 0) {}
        rv_next = nbsrc[t];
        rv_cur  = rv_next;
    }

    // prime nb (step 0) and y regs (wave-wide shuffles, predicated assign)
#pragma unroll
    for (int k = 0; k < C; ++k) {
        const float rg = __shfl(rv_cur, k);
        nb[k] = (t == 0 && GG > 1 && g > 0) ? rg : BIG;
    }
    float4 yva, yvb;
    {
        int cy0 = 0 - t; cy0 = cy0 < 0 ? 0 : cy0;
        yva = *(const float4*)&ylds[YIDX(cy0 * C)];
        yvb = *(const float4*)&ylds[YIDX(cy0 * C + 4)];
    }

    for (int s = 0; s < LSTEPS; ++s) {
        // head: boundary block prefetch (uniform branch, 1 float/lane)
        if (GG > 1 && g > 0 && (s & (BCH - 1)) == 0) {
            rv_cur = rv_next;
            const int b2 = s / BCH + 1;
            if (b2 < NBLK) {
                while (__hip_atomic_load(&nbflag[b2], __ATOMIC_ACQUIRE,
                                         __HIP_MEMORY_SCOPE_AGENT) == 0) {}
                rv_next = nbsrc[b2 * BLKF + t];
            }
        }

        const int c = s - t;
        const bool active = ((unsigned)c < (unsigned)NCH);
        float bt[C];
#pragma unroll
        for (int k = 0; k < C; ++k) bt[k] = BIG;   // pre-start lanes hand BIG down

        if (active) {
            const float yv[8] = {yva.x, yva.y, yva.z, yva.w,
                                 yvb.x, yvb.y, yvb.z, yvb.w};
            float dg = diagc;
#pragma unroll
            for (int k = 0; k < C; ++k) {
                float up = nb[k], dgv = dg;
#pragma unroll
                for (int r = 0; r < RR; ++r) {
                    const float old = carry[r];
                    const float v = fabsf(x[r] - yv[k]) +
                                    fminf(up, fminf(old, dgv));
                    carry[r] = v; up = v; dgv = old;
                }
                bt[k] = up;
                dg = nb[k];                        // diag for col k+1 = nb[k]
            }
            diagc = nb[C - 1];

            if (GG > 1 && g < GG - 1 && t == TPB - 1) {
                const int j0 = c * C;
                *(float4*)&gbuf[(size_t)g * N + j0]     = make_float4(bt[0], bt[1], bt[2], bt[3]);
                *(float4*)&gbuf[(size_t)g * N + j0 + 4] = make_float4(bt[4], bt[5], bt[6], bt[7]);
                // flag block b at c = 8b+9 (2 chunks late: stores already retired)
                if (c >= BCH + 1 && ((c - (BCH + 1)) & (BCH - 1)) == 0)
                    __hip_atomic_store(&flags[g * NBLK + (c - (BCH + 1)) / BCH], 1,
                                       __ATOMIC_RELEASE, __HIP_MEMORY_SCOPE_AGENT);
            }
        }

        // tail: handoff + prefetch for step s+1 (wave-wide, hidden by backedge)
        const int s1 = s + 1;
        const bool useNext = ((s1 & (BCH - 1)) == 0);
        const float rsrc = useNext ? rv_next : rv_cur;
        const int base = (s1 & (BCH - 1)) * C;
#pragma unroll
        for (int k = 0; k < C; ++k) {
            const float up1 = __shfl_up(bt[k], 1);
            const float rg  = __shfl(rsrc, base + k);
            nb[k] = (t == 0) ? ((GG > 1 && g > 0) ? rg : BIG) : up1;
        }
        int cy = s1 - t;
        cy = cy < 0 ? 0 : (cy > NCH - 1 ? NCH - 1 : cy);
        yva = *(const float4*)&ylds[YIDX(cy * C)];
        yvb = *(const float4*)&ylds[YIDX(cy * C + 4)];
    }

    if (GG > 1 && g < GG - 1 && t == TPB - 1)      // tail flag: last block
        __hip_atomic_store(&flags[g * NBLK + NBLK - 1], 1,
                           __ATOMIC_RELEASE, __HIP_MEMORY_SCOPE_AGENT);
    if (g == GG - 1 && t == TPB - 1) out[0] = carry[RR - 1];
}

extern "C" void kernel_launch(void* const* d_in, const int* in_sizes, int n_in,
                              void* d_out, int out_size, void* d_ws, size_t ws_size,
                              hipStream_t stream) {
    const float* src = (const float*)d_in[0];
    const float* tgt = (const float*)d_in[1];
    float* out = (float*)d_out;

    const size_t req = 4096 + 7 * (size_t)N * sizeof(float);
    if (ws_size >= req) {
        int*   flags = (int*)d_ws;
        float* gbuf  = (float*)((char*)d_ws + 4096);
        hipMemsetAsync(d_ws, 0, 4096, stream);     // fresh flags every call
        hipLaunchKernelGGL((dtw_wavepipe<8>), dim3(8), dim3(TPB), 0, stream,
                           src, tgt, out, gbuf, flags);
    } else {
        hipLaunchKernelGGL((dtw_wavepipe<1>), dim3(1), dim3(TPB), 0, stream,
                           src, tgt, out, (float*)nullptr, (int*)nullptr);
    }
}

// Round 6
// 562.370 us; speedup vs baseline: 1.6882x; 1.6882x over previous
//
#include <hip/hip_runtime.h>

// Exact DTW, single workgroup, 8 waves (2 per SIMD), barrier-thinned tile pipeline.
// Thread t owns RR=8 rows; columns in chunks of C=8; thread t runs chunk c at
// step s = start(t)+c with start(t) = t + KB*(t/64) (each wave skewed KB extra).
// Intra-wave neighbor handoff via LDS double buffer needs NO barrier: DS ops
// from one wave complete in order (lgkmcnt DS-to-DS is FIFO), and the per-step
// asm memory clobber pins compiler ordering. Wave-boundary handoff goes through
// a 32-entry LDS ring whose write->read and read->overwrite pairs are always
// separated by at least one __syncthreads (barrier every KB=8 steps).
// Co-resident waves (2/SIMD) hide each other's dependent-min chains and LDS
// latency, attacking the ~800cy/step overhead measured in R2/R4.

#define N      4096
#define TPB    512
#define RR     (N / TPB)      // 8 rows per thread
#define C      8              // columns per chunk
#define NCH    (N / C)        // 512 chunks
#define KB     8              // steps per barrier
#define RSZ    32             // ring entries per wave boundary (>= 2*KB safety)
#define NW     (TPB / 64)     // 8 waves
#define BS     (C + 1)        // bot row stride: 9 floats, coprime 32 banks
#define BIG    1e30f
#define YIDX(j) ((j) + (((j) >> 5) << 2))   // 16B pad per 32 floats
// last start = 511 + 8*7 = 567; last active step = 567 + 511 = 1078
#define STEPS  1080           // multiple of KB

__global__ __launch_bounds__(TPB, 1)
void dtw_mw(const float* __restrict__ xg, const float* __restrict__ yg,
            float* __restrict__ out) {
    __shared__ float ylds[N + (N >> 5) * 4];   // 18 KB
    __shared__ float bot[2][TPB * BS];         // 36 KB, intra-wave handoff
    __shared__ float ring[NW - 1][RSZ][C];     // 7 KB, wave-boundary handoff
    __shared__ float big8[C];                  // constant BIG source (row -1)

    const int t    = threadIdx.x;
    const int lane = t & 63;
    const int w    = t >> 6;

    for (int j4 = t * 4; j4 < N; j4 += TPB * 4)
        *(float4*)&ylds[YIDX(j4)] = *(const float4*)&yg[j4];
    if (t < C) big8[t] = BIG;

    float x[RR], carry[RR];
    const int i0 = t * RR;
#pragma unroll
    for (int r = 0; r < RR; ++r) { x[r] = xg[i0 + r]; carry[r] = BIG; }

    // D[i0-1][j0-1] at left edge of current chunk; (0,0): min(BIG,BIG,0)=0
    // reproduces D[0][0] = c[0][0] exactly.
    float diagc = (t == 0) ? 0.0f : BIG;
    const int start = t + KB * w;

    __syncthreads();

    for (int sb = 0; sb < STEPS; sb += KB) {
        for (int ss = 0; ss < KB; ++ss) {
            const int s = sb + ss;
            const int c = s - start;
            if ((unsigned)c < (unsigned)NCH) {
                // neighbor bottom-row source for this chunk
                const float* src =
                    (lane == 0) ? ((w == 0) ? big8
                                            : &ring[w - 1][c & (RSZ - 1)][0])
                                : &bot[(s + 1) & 1][(t - 1) * BS];
                // my bottom-row destination (lane 63 of waves 0..6 -> ring;
                // t = TPB-1 writes bot harmlessly, nobody reads it)
                float* dst = (lane == 63 && w < NW - 1)
                                 ? &ring[w][c & (RSZ - 1)][0]
                                 : &bot[s & 1][t * BS];

                float nbv[C];
#pragma unroll
                for (int k = 0; k < C; ++k) nbv[k] = src[k];   // load all up-front

                const int j0 = c * C;
                const float4 ya = *(const float4*)&ylds[YIDX(j0)];
                const float4 yb = *(const float4*)&ylds[YIDX(j0 + 4)];
                const float yv[C] = {ya.x, ya.y, ya.z, ya.w,
                                     yb.x, yb.y, yb.z, yb.w};

                float dg = diagc;
#pragma unroll
                for (int k = 0; k < C; ++k) {
                    float up = nbv[k], dgv = dg;
#pragma unroll
                    for (int r = 0; r < RR; ++r) {
                        const float old = carry[r];
                        const float v = fabsf(x[r] - yv[k]) +
                                        fminf(up, fminf(old, dgv));
                        carry[r] = v; up = v; dgv = old;
                    }
                    dst[k] = up;       // bottom cell of column j0+k
                    dg = nbv[k];       // diag for next column
                }
                diagc = dg;            // = nbv[C-1]
            }
            // pin compiler ordering of LDS ops across steps (intra-wave
            // correctness relies on program-order DS write->read)
            asm volatile("" ::: "memory");
        }
        __syncthreads();   // epoch barrier: orders all ring traffic
    }

    // D[N-1][N-1]: thread TPB-1, row RR-1
    if (t == TPB - 1) out[0] = carry[RR - 1];
}

extern "C" void kernel_launch(void* const* d_in, const int* in_sizes, int n_in,
                              void* d_out, int out_size, void* d_ws, size_t ws_size,
                              hipStream_t stream) {
    const float* src = (const float*)d_in[0];
    const float* tgt = (const float*)d_in[1];
    float* out = (float*)d_out;
    hipLaunchKernelGGL(dtw_mw, dim3(1), dim3(TPB), 0, stream, src, tgt, out);
}

// Round 7
// 550.629 us; speedup vs baseline: 1.7242x; 1.0213x over previous
//
#include <hip/hip_runtime.h>

// Exact DTW, single workgroup, 8 waves (2/SIMD), barrier-thinned tile pipeline,
// C=4 columns/chunk + tail-prefetched operands.
// Thread t owns RR=8 rows; runs chunk c at step s = start(t)+c,
// start(t) = t + KB*(t/64). Intra-wave neighbor handoff via LDS double buffer,
// no barrier (same-wave DS program order + per-step asm memory clobber).
// Wave-boundary handoff via 32-entry LDS ring, write->read separated by KB
// steps (>= 1 barrier; barrier every KB=8 steps).
// NEW vs R6: (a) C=4 halves per-step VALU (issue-bound regime) and cuts fill
// fraction; (b) nb/y for step s+1 are loaded at the TAIL of step s, so DS
// latency hides behind the loop back-edge instead of heading the min3 chain.

#define N      4096
#define TPB    512
#define RR     (N / TPB)      // 8 rows per thread
#define C      4              // columns per chunk
#define NCH    (N / C)        // 1024 chunks
#define KB     8              // steps per barrier
#define RSZ    32             // ring entries per wave boundary
#define NW     (TPB / 64)     // 8 waves
#define BS     (C + 1)        // bot stride 5, coprime 32 banks
#define BIG    1e30f
#define YIDX(j) ((j) + (((j) >> 5) << 2))   // 16B pad per 32 floats
// last start = 511 + 8*7 = 567; last active step = 567 + 1023 = 1590
#define STEPS  1592           // multiple of KB

__global__ __launch_bounds__(TPB, 1)
void dtw_mw2(const float* __restrict__ xg, const float* __restrict__ yg,
             float* __restrict__ out) {
    __shared__ float ylds[N + (N >> 5) * 4];   // 18 KB
    __shared__ float bot[2][TPB * BS];         // 20.5 KB
    __shared__ float ring[NW - 1][RSZ][C];     // 3.5 KB
    __shared__ float big4[C];

    const int t    = threadIdx.x;
    const int lane = t & 63;
    const int w    = t >> 6;

    for (int j4 = t * 4; j4 < N; j4 += TPB * 4)
        *(float4*)&ylds[YIDX(j4)] = *(const float4*)&yg[j4];
    if (t < C) big4[t] = BIG;

    float x[RR], carry[RR];
    const int i0 = t * RR;
#pragma unroll
    for (int r = 0; r < RR; ++r) { x[r] = xg[i0 + r]; carry[r] = BIG; }

    float diagc = (t == 0) ? 0.0f : BIG;   // (0,0): min3(BIG,BIG,0)=0 -> D[0][0]=c
    const int start = t + KB * w;

    // primed operands for the first active step (only t=0 starts at step 0;
    // its nb is genuinely BIG (row -1) and y is cols 0..3)
    float nb[C];
#pragma unroll
    for (int k = 0; k < C; ++k) nb[k] = BIG;
    float4 yv = *(const float4*)&ylds[YIDX(0)];

    __syncthreads();

    for (int sb = 0; sb < STEPS; sb += KB) {
        for (int ss = 0; ss < KB; ++ss) {
            const int s = sb + ss;
            const int c = s - start;

            if ((unsigned)c < (unsigned)NCH) {
                // my bottom-row destination: lane 63 of waves 0..6 -> ring
                float* dst = (lane == 63 && w < NW - 1)
                                 ? &ring[w][c & (RSZ - 1)][0]
                                 : &bot[s & 1][t * BS];
                const float yc[C] = {yv.x, yv.y, yv.z, yv.w};

                float dg = diagc;
#pragma unroll
                for (int k = 0; k < C; ++k) {
                    float up = nb[k], dgv = dg;
#pragma unroll
                    for (int r = 0; r < RR; ++r) {
                        const float old = carry[r];
                        const float v = fabsf(x[r] - yc[k]) +
                                        fminf(up, fminf(old, dgv));
                        carry[r] = v; up = v; dgv = old;
                    }
                    dst[k] = up;
                    dg = nb[k];
                }
                diagc = dg;   // = nb[C-1]
            }

            // ---- tail prefetch for step s+1 (chunk c1) ----
            // thread t-1 wrote chunk c1 bottoms into bot[s&1] during THIS step
            // (same wave => program order); ring entry was written KB steps ago
            // (>=1 barrier). Loads use safe addresses even when inactive.
            {
                const int c1 = s + 1 - start;
                const bool pf = ((unsigned)c1 < (unsigned)NCH);
                const float* src =
                    (lane == 0) ? ((w == 0) ? big4
                                            : &ring[w - 1][c1 & (RSZ - 1)][0])
                                : &bot[s & 1][(t - 1) * BS];
                float n0 = src[0], n1 = src[1], n2 = src[2], n3 = src[3];
                nb[0] = pf ? n0 : BIG;
                nb[1] = pf ? n1 : BIG;
                nb[2] = pf ? n2 : BIG;
                nb[3] = pf ? n3 : BIG;
                const int jc = pf ? c1 * C : 0;
                yv = *(const float4*)&ylds[YIDX(jc)];
            }
            asm volatile("" ::: "memory");   // pin DS op ordering across steps
        }
        __syncthreads();   // epoch barrier: orders all ring traffic
    }

    // D[N-1][N-1]: thread TPB-1, row RR-1
    if (t == TPB - 1) out[0] = carry[RR - 1];
}

extern "C" void kernel_launch(void* const* d_in, const int* in_sizes, int n_in,
                              void* d_out, int out_size, void* d_ws, size_t ws_size,
                              hipStream_t stream) {
    const float* src = (const float*)d_in[0];
    const float* tgt = (const float*)d_in[1];
    float* out = (float*)d_out;
    hipLaunchKernelGGL(dtw_mw2, dim3(1), dim3(TPB), 0, stream, src, tgt, out);
}